// Round 8
// baseline (1859.225 us; speedup 1.0000x reference)
//
#include <hip/hip_runtime.h>
#include <hip/hip_bf16.h>

// Resubmission #3: rounds 5-7 all died with UnresponsiveContainer on the
// same dead pod (infra). This source has never executed on hardware.

#define NN 100000   // nodes
#define NV 50000    // vars
#define NE 640000   // edges
#define FEAT 16
#define HD 128
#define NL 4
#define NI 20000    // n_int
#define KK 8
#define NPB 16      // nodes per block in GEMM-ish kernels
#define SCAN_BLK 98 // ceil(NN / 1024)

typedef __hip_bfloat16 bf16;

// ---------------- degree / norm ----------------
__global__ void k_deg_init(float* deg) {
    int i = blockIdx.x * blockDim.x + threadIdx.x;
    if (i < NN) deg[i] = 1.0f;
}

__global__ void k_deg_scatter(const int* __restrict__ ei, float* deg) {
    int e = blockIdx.x * blockDim.x + threadIdx.x;
    if (e < NE) atomicAdd(&deg[ei[NE + e]], 1.0f);
}

__global__ void k_deg_fin(const float* __restrict__ deg, float* dinv, float* selfn) {
    int i = blockIdx.x * blockDim.x + threadIdx.x;
    if (i < NN) {
        float d = deg[i];
        dinv[i]  = rsqrtf(d);
        selfn[i] = 1.0f / d;
    }
}

// ---------------- multi-block exclusive scan of in-degree counts ----------------
__global__ void k_scan_part(const float* __restrict__ deg, int* __restrict__ part) {
    __shared__ int s[256];
    const int t = threadIdx.x;
    const int i = blockIdx.x * 1024 + t * 4;
    int sum = 0;
#pragma unroll
    for (int j = 0; j < 4; ++j)
        if (i + j < NN) sum += (int)deg[i + j] - 1;
    s[t] = sum;
    __syncthreads();
    for (int off = 128; off > 0; off >>= 1) {
        if (t < off) s[t] += s[t + off];
        __syncthreads();
    }
    if (t == 0) part[blockIdx.x] = s[0];
}

__global__ void k_scan_mid(const int* __restrict__ part, int* __restrict__ blockoff,
                           int* __restrict__ row_ptr) {
    __shared__ int s[128];
    const int t = threadIdx.x;
    int v = (t < SCAN_BLK) ? part[t] : 0;
    s[t] = v;
    __syncthreads();
    for (int off = 1; off < 128; off <<= 1) {
        int u = (t >= off) ? s[t - off] : 0;
        __syncthreads();
        s[t] += u;
        __syncthreads();
    }
    if (t < SCAN_BLK) blockoff[t] = s[t] - v;   // exclusive
    if (t == 0) row_ptr[NN] = NE;
}

__global__ void k_scan_apply(const float* __restrict__ deg,
                             const int* __restrict__ blockoff,
                             int* __restrict__ row_ptr, int* __restrict__ cnt) {
    __shared__ int s[256];
    const int t = threadIdx.x;
    const int i = blockIdx.x * 1024 + t * 4;
    int c[4];
    int tsum = 0;
#pragma unroll
    for (int j = 0; j < 4; ++j) {
        c[j] = (i + j < NN) ? (int)deg[i + j] - 1 : 0;
        tsum += c[j];
    }
    s[t] = tsum;
    __syncthreads();
    for (int off = 1; off < 256; off <<= 1) {
        int u = (t >= off) ? s[t - off] : 0;
        __syncthreads();
        s[t] += u;
        __syncthreads();
    }
    int off = blockoff[blockIdx.x] + s[t] - tsum;   // exclusive within block
#pragma unroll
    for (int j = 0; j < 4; ++j) {
        if (i + j < NN) {
            row_ptr[i + j] = off;
            cnt[i + j] = 0;
            off += c[j];
        }
    }
}

__global__ void k_csr_fill(const int* __restrict__ ei,
                           const int* __restrict__ row_ptr, int* __restrict__ cnt,
                           const float* __restrict__ dinv,
                           int* __restrict__ col, float* __restrict__ wgt) {
    int e = blockIdx.x * blockDim.x + threadIdx.x;
    if (e >= NE) return;
    const int s = ei[e];
    const int d = ei[NE + e];
    const int pos = row_ptr[d] + atomicAdd(&cnt[d], 1);
    col[pos] = s;
    wgt[pos] = dinv[s] * dinv[d];
}

// ---------------- embedding MLP (16 -> 128 -> 128) ----------------
__global__ __launch_bounds__(HD) void k_embed(
                        const float* __restrict__ x,
                        const float* __restrict__ vW1, const float* __restrict__ vb1,
                        const float* __restrict__ vW2, const float* __restrict__ vb2,
                        const float* __restrict__ cW1, const float* __restrict__ cb1,
                        const float* __restrict__ cW2, const float* __restrict__ cb2,
                        float* __restrict__ h) {
    const int j = threadIdx.x;                       // 0..127 (output col)
    const int n0 = blockIdx.x * NPB;
    __shared__ float xs[NPB][FEAT];
    __shared__ float hid[NPB][HD];

    const float *W1, *b1, *W2, *b2;
    if (n0 < NV) { W1 = vW1; b1 = vb1; W2 = vW2; b2 = vb2; }
    else         { W1 = cW1; b1 = cb1; W2 = cW2; b2 = cb2; }

    // 128 threads load 16*16 = 256 x-values, coalesced
    xs[j >> 4][j & 15] = x[(size_t)n0 * FEAT + j];
    xs[8 + (j >> 4)][j & 15] = x[(size_t)n0 * FEAT + 128 + j];
    __syncthreads();

    float acc[NPB];
    const float bb1 = b1[j];
#pragma unroll
    for (int m = 0; m < NPB; ++m) acc[m] = bb1;
#pragma unroll
    for (int f = 0; f < FEAT; ++f) {
        const float w = W1[f * HD + j];
#pragma unroll
        for (int m = 0; m < NPB; ++m) acc[m] += xs[m][f] * w;
    }
#pragma unroll
    for (int m = 0; m < NPB; ++m) hid[m][j] = fmaxf(acc[m], 0.0f);
    __syncthreads();

    const float bb2 = b2[j];
#pragma unroll
    for (int m = 0; m < NPB; ++m) acc[m] = bb2;
#pragma unroll 8
    for (int k = 0; k < HD; ++k) {
        const float w = W2[k * HD + j];
#pragma unroll
        for (int m = 0; m < NPB; ++m) acc[m] += hid[m][k] * w;
    }
#pragma unroll
    for (int m = 0; m < NPB; ++m) h[(size_t)(n0 + m) * HD + j] = acc[m];
}

// ---------------- hw = h @ conv_W[l]  (bf16 output) ----------------
__global__ __launch_bounds__(HD) void k_hw(
                     const float* __restrict__ h, const float* __restrict__ W,
                     bf16* __restrict__ hw) {
    const int j = threadIdx.x;
    const int n0 = blockIdx.x * NPB;
    __shared__ float hs[NPB][HD];
#pragma unroll
    for (int m = 0; m < NPB; ++m) hs[m][j] = h[(size_t)(n0 + m) * HD + j];
    __syncthreads();

    float acc[NPB];
#pragma unroll
    for (int m = 0; m < NPB; ++m) acc[m] = 0.0f;
#pragma unroll 8
    for (int k = 0; k < HD; ++k) {
        const float w = W[k * HD + j];
#pragma unroll
        for (int m = 0; m < NPB; ++m) acc[m] += hs[m][k] * w;
    }
#pragma unroll
    for (int m = 0; m < NPB; ++m) hw[(size_t)(n0 + m) * HD + j] = __float2bfloat16(acc[m]);
}

// ---------------- gather + combine + refine MLP + residual ----------------
__global__ __launch_bounds__(HD) void k_combine(
                          const bf16* __restrict__ hw,
                          const int* __restrict__ row_ptr,
                          const int* __restrict__ col,
                          const float* __restrict__ wgt,
                          const float* __restrict__ selfn,
                          const float* __restrict__ cb,
                          const float* __restrict__ W1, const float* __restrict__ b1,
                          const float* __restrict__ W2, const float* __restrict__ b2,
                          float* __restrict__ h) {
    const int j = threadIdx.x;
    const int n0 = blockIdx.x * NPB;
    __shared__ float hs[NPB][HD];
    __shared__ float hid[NPB][HD];

    const float cbj = cb[j];
#pragma unroll
    for (int m = 0; m < NPB; ++m) {
        const int node = n0 + m;
        float agg = __bfloat162float(hw[(size_t)node * HD + j]) * selfn[node] + cbj;
        const int e0 = row_ptr[node], e1 = row_ptr[node + 1];
        for (int e = e0; e < e1; ++e) {
            agg += wgt[e] * __bfloat162float(hw[(size_t)col[e] * HD + j]);
        }
        hs[m][j] = fmaxf(agg, 0.0f);
    }
    __syncthreads();

    float acc[NPB];
    const float bb1 = b1[j];
#pragma unroll
    for (int m = 0; m < NPB; ++m) acc[m] = bb1;
#pragma unroll 8
    for (int k = 0; k < HD; ++k) {
        const float w = W1[k * HD + j];
#pragma unroll
        for (int m = 0; m < NPB; ++m) acc[m] += hs[m][k] * w;
    }
#pragma unroll
    for (int m = 0; m < NPB; ++m) hid[m][j] = fmaxf(acc[m], 0.0f);
    __syncthreads();

    const float bb2 = b2[j];
#pragma unroll
    for (int m = 0; m < NPB; ++m) acc[m] = bb2;
#pragma unroll 8
    for (int k = 0; k < HD; ++k) {
        const float w = W2[k * HD + j];
#pragma unroll
        for (int m = 0; m < NPB; ++m) acc[m] += hid[m][k] * w;
    }
#pragma unroll
    for (int m = 0; m < NPB; ++m) h[(size_t)(n0 + m) * HD + j] += acc[m];
}

// ---------------- bernoulli head: (128 -> 64 -> 1) ----------------
__global__ void k_bern(const float* __restrict__ h,
                       const float* __restrict__ W1, const float* __restrict__ b1,
                       const float* __restrict__ W2, const float* __restrict__ b2,
                       float* __restrict__ out) {
    const long long t = (long long)blockIdx.x * blockDim.x + threadIdx.x;
    const int n = (int)(t >> 6);
    const int lane = (int)(t & 63);
    if (n >= NV) return;
    const float* hn = h + (size_t)n * HD;
    float acc = b1[lane];
#pragma unroll 8
    for (int k = 0; k < HD; ++k) acc += hn[k] * W1[k * 64 + lane];
    float p = fmaxf(acc, 0.0f) * W2[lane];
#pragma unroll
    for (int off = 32; off > 0; off >>= 1) p += __shfl_down(p, off);
    if (lane == 0) out[n] = p + b2[0];
}

// ---------------- categorical head: einsum nh,nhk->nk ----------------
__global__ void k_cat(const float* __restrict__ h,
                      const float* __restrict__ cW, const float* __restrict__ cb,
                      float* __restrict__ out) {
    const long long t = (long long)blockIdx.x * blockDim.x + threadIdx.x;
    const int n = (int)(t >> 6);
    const int lane = (int)(t & 63);
    if (n >= NI) return;
    const float* hn = h + (size_t)n * HD;
    float p[KK];
#pragma unroll
    for (int k = 0; k < KK; ++k) p[k] = 0.0f;
#pragma unroll
    for (int half = 0; half < 2; ++half) {
        const int hh = lane + 64 * half;
        const float vh = hn[hh];
        const float* wp = cW + ((size_t)n * HD + hh) * KK;
#pragma unroll
        for (int k = 0; k < KK; ++k) p[k] += vh * wp[k];
    }
#pragma unroll
    for (int k = 0; k < KK; ++k) {
#pragma unroll
        for (int off = 32; off > 0; off >>= 1) p[k] += __shfl_down(p[k], off);
    }
    if (lane == 0) {
#pragma unroll
        for (int k = 0; k < KK; ++k) out[NV + (size_t)n * KK + k] = p[k] + cb[(size_t)n * KK + k];
    }
}

extern "C" void kernel_launch(void* const* d_in, const int* in_sizes, int n_in,
                              void* d_out, int out_size, void* d_ws, size_t ws_size,
                              hipStream_t stream) {
    const float* x  = (const float*)d_in[0];
    const int*   ei = (const int*)d_in[1];   // int inputs arrive as int32
    // d_in[2] = num_vars scalar (hardcoded NV)
    const float* ve_W1 = (const float*)d_in[3];
    const float* ve_b1 = (const float*)d_in[4];
    const float* ve_W2 = (const float*)d_in[5];
    const float* ve_b2 = (const float*)d_in[6];
    const float* ce_W1 = (const float*)d_in[7];
    const float* ce_b1 = (const float*)d_in[8];
    const float* ce_W2 = (const float*)d_in[9];
    const float* ce_b2 = (const float*)d_in[10];
    const float* conv_W = (const float*)d_in[11];
    const float* conv_b = (const float*)d_in[12];
    const float* ref_W1 = (const float*)d_in[13];
    const float* ref_b1 = (const float*)d_in[14];
    const float* ref_W2 = (const float*)d_in[15];
    const float* ref_b2 = (const float*)d_in[16];
    const float* bh_W1 = (const float*)d_in[17];
    const float* bh_b1 = (const float*)d_in[18];
    const float* bh_W2 = (const float*)d_in[19];
    const float* bh_b2 = (const float*)d_in[20];
    const float* cat_W = (const float*)d_in[21];
    const float* cat_b = (const float*)d_in[22];
    float* out = (float*)d_out;

    // ---- workspace layout (~80 MiB total) ----
    const size_t need = (size_t)(3 * NN + (NN + 1) + NN + 2 * NE + 2 * SCAN_BLK) * 4
                      + (size_t)NN * HD * 4 + (size_t)NN * HD * 2;
    if (ws_size < need) return;

    float* deg     = (float*)d_ws;                   // NN
    float* dinv    = deg + NN;                       // NN
    float* selfn   = dinv + NN;                      // NN
    int*   row_ptr = (int*)(selfn + NN);             // NN+1
    int*   cnt     = row_ptr + (NN + 1);             // NN
    int*   col     = cnt + NN;                       // NE
    float* wgt     = (float*)(col + NE);             // NE
    int*   part    = (int*)(wgt + NE);               // SCAN_BLK
    int*   blockoff= part + SCAN_BLK;                // SCAN_BLK
    float* h       = (float*)(blockoff + SCAN_BLK);  // NN*HD fp32
    bf16*  hwb     = (bf16*)(h + (size_t)NN * HD);   // NN*HD bf16

    // degree / norms / CSR
    k_deg_init<<<(NN + 255) / 256, 256, 0, stream>>>(deg);
    k_deg_scatter<<<(NE + 255) / 256, 256, 0, stream>>>(ei, deg);
    k_deg_fin<<<(NN + 255) / 256, 256, 0, stream>>>(deg, dinv, selfn);
    k_scan_part<<<SCAN_BLK, 256, 0, stream>>>(deg, part);
    k_scan_mid<<<1, 128, 0, stream>>>(part, blockoff, row_ptr);
    k_scan_apply<<<SCAN_BLK, 256, 0, stream>>>(deg, blockoff, row_ptr, cnt);
    k_csr_fill<<<(NE + 255) / 256, 256, 0, stream>>>(ei, row_ptr, cnt, dinv, col, wgt);

    // embedding
    k_embed<<<NN / NPB, HD, 0, stream>>>(x, ve_W1, ve_b1, ve_W2, ve_b2,
                                         ce_W1, ce_b1, ce_W2, ce_b2, h);

    // conv layers
    for (int l = 0; l < NL; ++l) {
        k_hw<<<NN / NPB, HD, 0, stream>>>(h, conv_W + (size_t)l * HD * HD, hwb);
        k_combine<<<NN / NPB, HD, 0, stream>>>(hwb, row_ptr, col, wgt, selfn,
                                               conv_b + (size_t)l * HD,
                                               ref_W1 + (size_t)l * HD * HD,
                                               ref_b1 + (size_t)l * HD,
                                               ref_W2 + (size_t)l * HD * HD,
                                               ref_b2 + (size_t)l * HD,
                                               h);
    }

    // heads
    k_bern<<<(NV * 64) / 256, 256, 0, stream>>>(h, bh_W1, bh_b1, bh_W2, bh_b2, out);
    k_cat<<<(NI * 64) / 256, 256, 0, stream>>>(h, cat_W, cat_b, out);
}

// Round 9
// 1638.040 us; speedup vs baseline: 1.1350x; 1.1350x over previous
//
#include <hip/hip_runtime.h>
#include <hip/hip_bf16.h>

#define NN 100000   // nodes
#define NV 50000    // vars
#define NE 640000   // edges
#define FEAT 16
#define HD 128
#define NL 4
#define NI 20000    // n_int
#define KK 8
#define NPB 16      // nodes per block in GEMM-ish kernels
#define SCAN_BLK 98 // ceil(NN / 1024)

typedef __hip_bfloat16 bf16;

// ---------------- degree / norm ----------------
__global__ void k_deg_init(float* deg) {
    int i = blockIdx.x * blockDim.x + threadIdx.x;
    if (i < NN) deg[i] = 1.0f;
}

__global__ void k_deg_scatter(const int* __restrict__ ei, float* deg) {
    int e = blockIdx.x * blockDim.x + threadIdx.x;
    if (e < NE) atomicAdd(&deg[ei[NE + e]], 1.0f);
}

__global__ void k_deg_fin(const float* __restrict__ deg, float* dinv, float* selfn) {
    int i = blockIdx.x * blockDim.x + threadIdx.x;
    if (i < NN) {
        float d = deg[i];
        dinv[i]  = rsqrtf(d);
        selfn[i] = 1.0f / d;
    }
}

// ---------------- multi-block exclusive scan of in-degree counts ----------------
__global__ void k_scan_part(const float* __restrict__ deg, int* __restrict__ part) {
    __shared__ int s[256];
    const int t = threadIdx.x;
    const int i = blockIdx.x * 1024 + t * 4;
    int sum = 0;
#pragma unroll
    for (int j = 0; j < 4; ++j)
        if (i + j < NN) sum += (int)deg[i + j] - 1;
    s[t] = sum;
    __syncthreads();
    for (int off = 128; off > 0; off >>= 1) {
        if (t < off) s[t] += s[t + off];
        __syncthreads();
    }
    if (t == 0) part[blockIdx.x] = s[0];
}

__global__ void k_scan_mid(const int* __restrict__ part, int* __restrict__ blockoff,
                           int* __restrict__ row_ptr) {
    __shared__ int s[128];
    const int t = threadIdx.x;
    int v = (t < SCAN_BLK) ? part[t] : 0;
    s[t] = v;
    __syncthreads();
    for (int off = 1; off < 128; off <<= 1) {
        int u = (t >= off) ? s[t - off] : 0;
        __syncthreads();
        s[t] += u;
        __syncthreads();
    }
    if (t < SCAN_BLK) blockoff[t] = s[t] - v;   // exclusive
    if (t == 0) row_ptr[NN] = NE;
}

__global__ void k_scan_apply(const float* __restrict__ deg,
                             const int* __restrict__ blockoff,
                             int* __restrict__ row_ptr, int* __restrict__ cnt) {
    __shared__ int s[256];
    const int t = threadIdx.x;
    const int i = blockIdx.x * 1024 + t * 4;
    int c[4];
    int tsum = 0;
#pragma unroll
    for (int j = 0; j < 4; ++j) {
        c[j] = (i + j < NN) ? (int)deg[i + j] - 1 : 0;
        tsum += c[j];
    }
    s[t] = tsum;
    __syncthreads();
    for (int off = 1; off < 256; off <<= 1) {
        int u = (t >= off) ? s[t - off] : 0;
        __syncthreads();
        s[t] += u;
        __syncthreads();
    }
    int off = blockoff[blockIdx.x] + s[t] - tsum;   // exclusive within block
#pragma unroll
    for (int j = 0; j < 4; ++j) {
        if (i + j < NN) {
            row_ptr[i + j] = off;
            cnt[i + j] = 0;
            off += c[j];
        }
    }
}

__global__ void k_csr_fill(const int* __restrict__ ei,
                           const int* __restrict__ row_ptr, int* __restrict__ cnt,
                           const float* __restrict__ dinv,
                           int* __restrict__ col, float* __restrict__ wgt) {
    int e = blockIdx.x * blockDim.x + threadIdx.x;
    if (e >= NE) return;
    const int s = ei[e];
    const int d = ei[NE + e];
    const int pos = row_ptr[d] + atomicAdd(&cnt[d], 1);
    col[pos] = s;
    wgt[pos] = dinv[s] * dinv[d];
}

// ---------------- embedding MLP (16 -> 128 -> 128) ----------------
__global__ __launch_bounds__(HD) void k_embed(
                        const float* __restrict__ x,
                        const float* __restrict__ vW1, const float* __restrict__ vb1,
                        const float* __restrict__ vW2, const float* __restrict__ vb2,
                        const float* __restrict__ cW1, const float* __restrict__ cb1,
                        const float* __restrict__ cW2, const float* __restrict__ cb2,
                        float* __restrict__ h) {
    const int j = threadIdx.x;                       // 0..127 (output col)
    const int n0 = blockIdx.x * NPB;
    __shared__ float xs[NPB][FEAT];
    __shared__ float hid[NPB][HD];

    const float *W1, *b1, *W2, *b2;
    if (n0 < NV) { W1 = vW1; b1 = vb1; W2 = vW2; b2 = vb2; }
    else         { W1 = cW1; b1 = cb1; W2 = cW2; b2 = cb2; }

    // 128 threads load 16*16 = 256 x-values, coalesced
    xs[j >> 4][j & 15] = x[(size_t)n0 * FEAT + j];
    xs[8 + (j >> 4)][j & 15] = x[(size_t)n0 * FEAT + 128 + j];
    __syncthreads();

    float acc[NPB];
    const float bb1 = b1[j];
#pragma unroll
    for (int m = 0; m < NPB; ++m) acc[m] = bb1;
#pragma unroll
    for (int f = 0; f < FEAT; ++f) {
        const float w = W1[f * HD + j];
#pragma unroll
        for (int m = 0; m < NPB; ++m) acc[m] += xs[m][f] * w;
    }
#pragma unroll
    for (int m = 0; m < NPB; ++m) hid[m][j] = fmaxf(acc[m], 0.0f);
    __syncthreads();

    const float bb2 = b2[j];
#pragma unroll
    for (int m = 0; m < NPB; ++m) acc[m] = bb2;
#pragma unroll 8
    for (int k = 0; k < HD; ++k) {
        const float w = W2[k * HD + j];
#pragma unroll
        for (int m = 0; m < NPB; ++m) acc[m] += hid[m][k] * w;
    }
#pragma unroll
    for (int m = 0; m < NPB; ++m) h[(size_t)(n0 + m) * HD + j] = acc[m];
}

// ---------------- hw = h @ conv_W[l]  (bf16 output) ----------------
__global__ __launch_bounds__(HD) void k_hw(
                     const float* __restrict__ h, const float* __restrict__ W,
                     bf16* __restrict__ hw) {
    const int j = threadIdx.x;
    const int n0 = blockIdx.x * NPB;
    __shared__ float hs[NPB][HD];
#pragma unroll
    for (int m = 0; m < NPB; ++m) hs[m][j] = h[(size_t)(n0 + m) * HD + j];
    __syncthreads();

    float acc[NPB];
#pragma unroll
    for (int m = 0; m < NPB; ++m) acc[m] = 0.0f;
#pragma unroll 8
    for (int k = 0; k < HD; ++k) {
        const float w = W[k * HD + j];
#pragma unroll
        for (int m = 0; m < NPB; ++m) acc[m] += hs[m][k] * w;
    }
#pragma unroll
    for (int m = 0; m < NPB; ++m) hw[(size_t)(n0 + m) * HD + j] = __float2bfloat16(acc[m]);
}

// ---------------- gather + combine + refine MLP + residual ----------------
// Gather uses lockstep rounds across the block's NPB nodes: per round, NPB
// INDEPENDENT predicated loads are in flight (vs a serial per-node edge
// chain), hiding the random-row-gather latency. Exhausted nodes clamp to
// edge 0 with weight 0 (safe, L2-hot address) to keep the body branch-free.
__global__ __launch_bounds__(HD) void k_combine(
                          const bf16* __restrict__ hw,
                          const int* __restrict__ row_ptr,
                          const int* __restrict__ col,
                          const float* __restrict__ wgt,
                          const float* __restrict__ selfn,
                          const float* __restrict__ cb,
                          const float* __restrict__ W1, const float* __restrict__ b1,
                          const float* __restrict__ W2, const float* __restrict__ b2,
                          float* __restrict__ h) {
    const int j = threadIdx.x;
    const int n0 = blockIdx.x * NPB;
    __shared__ float hs[NPB][HD];
    __shared__ float hid[NPB][HD];
    __shared__ int rp[NPB + 1];

    if (j <= NPB) rp[j] = row_ptr[n0 + j];
    __syncthreads();

    float acc[NPB];
    const float cbj = cb[j];
#pragma unroll
    for (int m = 0; m < NPB; ++m)
        acc[m] = __bfloat162float(hw[(size_t)(n0 + m) * HD + j]) * selfn[n0 + m] + cbj;

    int ecur[NPB], eend[NPB];
    int rounds = 0;
#pragma unroll
    for (int m = 0; m < NPB; ++m) {
        ecur[m] = rp[m];
        eend[m] = rp[m + 1];
        rounds = max(rounds, eend[m] - ecur[m]);
    }

    for (int r = 0; r < rounds; ++r) {
#pragma unroll
        for (int m = 0; m < NPB; ++m) {
            const bool live = ecur[m] < eend[m];
            const int  e    = live ? ecur[m] : 0;
            const float w   = live ? wgt[e] : 0.0f;
            acc[m] += w * __bfloat162float(hw[(size_t)col[e] * HD + j]);
            ecur[m] += live ? 1 : 0;
        }
    }

#pragma unroll
    for (int m = 0; m < NPB; ++m) hs[m][j] = fmaxf(acc[m], 0.0f);
    __syncthreads();

    const float bb1 = b1[j];
#pragma unroll
    for (int m = 0; m < NPB; ++m) acc[m] = bb1;
#pragma unroll 8
    for (int k = 0; k < HD; ++k) {
        const float w = W1[k * HD + j];
#pragma unroll
        for (int m = 0; m < NPB; ++m) acc[m] += hs[m][k] * w;
    }
#pragma unroll
    for (int m = 0; m < NPB; ++m) hid[m][j] = fmaxf(acc[m], 0.0f);
    __syncthreads();

    const float bb2 = b2[j];
#pragma unroll
    for (int m = 0; m < NPB; ++m) acc[m] = bb2;
#pragma unroll 8
    for (int k = 0; k < HD; ++k) {
        const float w = W2[k * HD + j];
#pragma unroll
        for (int m = 0; m < NPB; ++m) acc[m] += hid[m][k] * w;
    }
#pragma unroll
    for (int m = 0; m < NPB; ++m) h[(size_t)(n0 + m) * HD + j] += acc[m];
}

// ---------------- bernoulli head: (128 -> 64 -> 1) ----------------
__global__ void k_bern(const float* __restrict__ h,
                       const float* __restrict__ W1, const float* __restrict__ b1,
                       const float* __restrict__ W2, const float* __restrict__ b2,
                       float* __restrict__ out) {
    const long long t = (long long)blockIdx.x * blockDim.x + threadIdx.x;
    const int n = (int)(t >> 6);
    const int lane = (int)(t & 63);
    if (n >= NV) return;
    const float* hn = h + (size_t)n * HD;
    float acc = b1[lane];
#pragma unroll 8
    for (int k = 0; k < HD; ++k) acc += hn[k] * W1[k * 64 + lane];
    float p = fmaxf(acc, 0.0f) * W2[lane];
#pragma unroll
    for (int off = 32; off > 0; off >>= 1) p += __shfl_down(p, off);
    if (lane == 0) out[n] = p + b2[0];
}

// ---------------- categorical head: einsum nh,nhk->nk ----------------
__global__ void k_cat(const float* __restrict__ h,
                      const float* __restrict__ cW, const float* __restrict__ cb,
                      float* __restrict__ out) {
    const long long t = (long long)blockIdx.x * blockDim.x + threadIdx.x;
    const int n = (int)(t >> 6);
    const int lane = (int)(t & 63);
    if (n >= NI) return;
    const float* hn = h + (size_t)n * HD;
    float p[KK];
#pragma unroll
    for (int k = 0; k < KK; ++k) p[k] = 0.0f;
#pragma unroll
    for (int half = 0; half < 2; ++half) {
        const int hh = lane + 64 * half;
        const float vh = hn[hh];
        const float* wp = cW + ((size_t)n * HD + hh) * KK;
#pragma unroll
        for (int k = 0; k < KK; ++k) p[k] += vh * wp[k];
    }
#pragma unroll
    for (int k = 0; k < KK; ++k) {
#pragma unroll
        for (int off = 32; off > 0; off >>= 1) p[k] += __shfl_down(p[k], off);
    }
    if (lane == 0) {
#pragma unroll
        for (int k = 0; k < KK; ++k) out[NV + (size_t)n * KK + k] = p[k] + cb[(size_t)n * KK + k];
    }
}

extern "C" void kernel_launch(void* const* d_in, const int* in_sizes, int n_in,
                              void* d_out, int out_size, void* d_ws, size_t ws_size,
                              hipStream_t stream) {
    const float* x  = (const float*)d_in[0];
    const int*   ei = (const int*)d_in[1];   // int inputs arrive as int32
    // d_in[2] = num_vars scalar (hardcoded NV)
    const float* ve_W1 = (const float*)d_in[3];
    const float* ve_b1 = (const float*)d_in[4];
    const float* ve_W2 = (const float*)d_in[5];
    const float* ve_b2 = (const float*)d_in[6];
    const float* ce_W1 = (const float*)d_in[7];
    const float* ce_b1 = (const float*)d_in[8];
    const float* ce_W2 = (const float*)d_in[9];
    const float* ce_b2 = (const float*)d_in[10];
    const float* conv_W = (const float*)d_in[11];
    const float* conv_b = (const float*)d_in[12];
    const float* ref_W1 = (const float*)d_in[13];
    const float* ref_b1 = (const float*)d_in[14];
    const float* ref_W2 = (const float*)d_in[15];
    const float* ref_b2 = (const float*)d_in[16];
    const float* bh_W1 = (const float*)d_in[17];
    const float* bh_b1 = (const float*)d_in[18];
    const float* bh_W2 = (const float*)d_in[19];
    const float* bh_b2 = (const float*)d_in[20];
    const float* cat_W = (const float*)d_in[21];
    const float* cat_b = (const float*)d_in[22];
    float* out = (float*)d_out;

    // ---- workspace layout (~80 MiB total) ----
    const size_t need = (size_t)(3 * NN + (NN + 1) + NN + 2 * NE + 2 * SCAN_BLK) * 4
                      + (size_t)NN * HD * 4 + (size_t)NN * HD * 2;
    if (ws_size < need) return;

    float* deg     = (float*)d_ws;                   // NN
    float* dinv    = deg + NN;                       // NN
    float* selfn   = dinv + NN;                      // NN
    int*   row_ptr = (int*)(selfn + NN);             // NN+1
    int*   cnt     = row_ptr + (NN + 1);             // NN
    int*   col     = cnt + NN;                       // NE
    float* wgt     = (float*)(col + NE);             // NE
    int*   part    = (int*)(wgt + NE);               // SCAN_BLK
    int*   blockoff= part + SCAN_BLK;                // SCAN_BLK
    float* h       = (float*)(blockoff + SCAN_BLK);  // NN*HD fp32
    bf16*  hwb     = (bf16*)(h + (size_t)NN * HD);   // NN*HD bf16

    // degree / norms / CSR
    k_deg_init<<<(NN + 255) / 256, 256, 0, stream>>>(deg);
    k_deg_scatter<<<(NE + 255) / 256, 256, 0, stream>>>(ei, deg);
    k_deg_fin<<<(NN + 255) / 256, 256, 0, stream>>>(deg, dinv, selfn);
    k_scan_part<<<SCAN_BLK, 256, 0, stream>>>(deg, part);
    k_scan_mid<<<1, 128, 0, stream>>>(part, blockoff, row_ptr);
    k_scan_apply<<<SCAN_BLK, 256, 0, stream>>>(deg, blockoff, row_ptr, cnt);
    k_csr_fill<<<(NE + 255) / 256, 256, 0, stream>>>(ei, row_ptr, cnt, dinv, col, wgt);

    // embedding
    k_embed<<<NN / NPB, HD, 0, stream>>>(x, ve_W1, ve_b1, ve_W2, ve_b2,
                                         ce_W1, ce_b1, ce_W2, ce_b2, h);

    // conv layers
    for (int l = 0; l < NL; ++l) {
        k_hw<<<NN / NPB, HD, 0, stream>>>(h, conv_W + (size_t)l * HD * HD, hwb);
        k_combine<<<NN / NPB, HD, 0, stream>>>(hwb, row_ptr, col, wgt, selfn,
                                               conv_b + (size_t)l * HD,
                                               ref_W1 + (size_t)l * HD * HD,
                                               ref_b1 + (size_t)l * HD,
                                               ref_W2 + (size_t)l * HD * HD,
                                               ref_b2 + (size_t)l * HD,
                                               h);
    }

    // heads
    k_bern<<<(NV * 64) / 256, 256, 0, stream>>>(h, bh_W1, bh_b1, bh_W2, bh_b2, out);
    k_cat<<<(NI * 64) / 256, 256, 0, stream>>>(h, cat_W, cat_b, out);
}